// Round 1
// baseline (4472.746 us; speedup 1.0000x reference)
//
#include <hip/hip_runtime.h>
#include <hip/hip_bf16.h>
#include <math.h>

#define T_TOKENS 8192
#define DIM      1024
#define INTER    2048
#define NE       8
#define CAP      16896   // 2*T + NE*64 (per-expert 64-row padding), fixed upper bound

// ---------- helpers ----------
__device__ __forceinline__ float bf2f(unsigned short u) {
  return __uint_as_float(((unsigned int)u) << 16);
}
__device__ __forceinline__ unsigned short f2bf(float f) {
  unsigned int u = __float_as_uint(f);
  unsigned int r = 0x7FFFu + ((u >> 16) & 1u);
  return (unsigned short)((u + r) >> 16);
}
__device__ __forceinline__ float silu_f(float v) {
  return v / (1.0f + expf(-v));
}

// ---------- kernel 0: zero the counters ----------
__global__ void init_kernel(int* __restrict__ cnt, int* __restrict__ fill) {
  int i = threadIdx.x;
  if (i < NE) { cnt[i] = 0; fill[i] = 0; }
}

// ---------- kernel 1: gate (softmax + bias + top2) ----------
// one wave per token; 4 waves per block
__global__ __launch_bounds__(256) void gate_kernel(
    const float* __restrict__ x, const float* __restrict__ gw,
    const float* __restrict__ gb, int* __restrict__ cnt,
    int* __restrict__ topk_idx, float* __restrict__ topk_w) {
  const int wave = threadIdx.x >> 6;
  const int lane = threadIdx.x & 63;
  const int t = blockIdx.x * 4 + wave;
  if (t >= T_TOKENS) return;
  const float* xt = x + (size_t)t * DIM;

  float p[NE];
#pragma unroll
  for (int e = 0; e < NE; e++) p[e] = 0.0f;
  for (int d = lane; d < DIM; d += 64) {
    float xv = xt[d];
#pragma unroll
    for (int e = 0; e < NE; e++) p[e] += xv * gw[e * DIM + d];
  }
#pragma unroll
  for (int e = 0; e < NE; e++) {
#pragma unroll
    for (int off = 32; off > 0; off >>= 1) p[e] += __shfl_xor(p[e], off, 64);
  }
  if (lane == 0) {
    float m = p[0];
#pragma unroll
    for (int e = 1; e < NE; e++) m = fmaxf(m, p[e]);
    float s[NE]; float den = 0.0f;
#pragma unroll
    for (int e = 0; e < NE; e++) { s[e] = expf(p[e] - m); den += s[e]; }
    float inv = 1.0f / den;
    float sc[NE], bi[NE];
#pragma unroll
    for (int e = 0; e < NE; e++) { sc[e] = s[e] * inv; bi[e] = sc[e] + gb[e]; }
    // top-2 on biased scores, ties -> lowest index (matches lax.top_k)
    int i0 = 0; float b0 = bi[0];
#pragma unroll
    for (int e = 1; e < NE; e++) if (bi[e] > b0) { b0 = bi[e]; i0 = e; }
    int i1 = -1; float b1 = -1e30f;
#pragma unroll
    for (int e = 0; e < NE; e++) if (e != i0 && bi[e] > b1) { b1 = bi[e]; i1 = e; }
    topk_idx[t * 2 + 0] = i0;
    topk_idx[t * 2 + 1] = i1;
    topk_w[t * 2 + 0] = sc[i0];   // ROUTE_SCALE == 1.0
    topk_w[t * 2 + 1] = sc[i1];
    atomicAdd(&cnt[i0], 1);
    atomicAdd(&cnt[i1], 1);
  }
}

// ---------- kernel 2: scatter token->expert pair lists ----------
__global__ __launch_bounds__(256) void scatter_kernel(
    const int* __restrict__ cnt, int* __restrict__ fill,
    const int* __restrict__ topk_idx, const float* __restrict__ topk_w,
    int* __restrict__ pair_tok, float* __restrict__ pair_w) {
  int t = blockIdx.x * blockDim.x + threadIdx.x;
  if (t >= T_TOKENS) return;
  int offp[NE];
  int o = 0;
#pragma unroll
  for (int e = 0; e < NE; e++) { offp[e] = o; o += (cnt[e] + 63) & ~63; }
#pragma unroll
  for (int k = 0; k < 2; k++) {
    int e = topk_idx[t * 2 + k];
    int pos = atomicAdd(&fill[e], 1);
    int p = offp[e] + pos;
    pair_tok[p] = t;
    pair_w[p] = topk_w[t * 2 + k];
  }
}

// ---------- GEMM 1: h = silu(x@w1^T) * (x@w3^T), bf16 out ----------
// BM=BN=64, BK=16, 256 threads, 4x4 acc per thread (x2 matrices)
template <bool ROUTED>
__global__ __launch_bounds__(256) void h_kernel(
    const float* __restrict__ x, const float* __restrict__ w1all,
    const float* __restrict__ w3all, const int* __restrict__ cnt,
    const int* __restrict__ pair_tok, unsigned short* __restrict__ H) {
  const int p0 = blockIdx.y * 64;
  int realEnd;
  const float* w1e;
  const float* w3e;
  if (ROUTED) {
    int base = 0, eSel = -1; realEnd = 0;
    for (int i = 0; i < NE; i++) {
      int c = cnt[i];
      int pad = (c + 63) & ~63;
      if (eSel < 0) {
        if (p0 < base + pad) { eSel = i; realEnd = base + c; }
        else base += pad;
      }
    }
    if (eSel < 0 || p0 >= realEnd) return;
    w1e = w1all + (size_t)eSel * INTER * DIM;
    w3e = w3all + (size_t)eSel * INTER * DIM;
  } else {
    realEnd = T_TOKENS;
    w1e = w1all;
    w3e = w3all;
  }

  const int tid = threadIdx.x;
  const int r = tid >> 2;            // 0..63 (tile row for loads)
  const int c4 = (tid & 3) * 4;      // 0,4,8,12 (k offset for loads)
  const int tx = tid & 15;           // n subtile
  const int ty = tid >> 4;           // m subtile
  const int n0 = blockIdx.x * 64;

  int tokr;
  if (ROUTED) {
    int pRow = p0 + r;
    tokr = (pRow < realEnd) ? pair_tok[pRow] : pair_tok[p0];
  } else {
    tokr = p0 + r;
  }
  const float* xrow = x + (size_t)tokr * DIM;
  const float* w1row = w1e + (size_t)(n0 + r) * DIM;
  const float* w3row = w3e + (size_t)(n0 + r) * DIM;

  __shared__ float As[16][64];
  __shared__ float B1[16][64];
  __shared__ float B3[16][64];

  float acc1[4][4] = {};
  float acc3[4][4] = {};

  for (int k0 = 0; k0 < DIM; k0 += 16) {
    const float4 av = *(const float4*)(xrow + k0 + c4);
    const float4 b1v = *(const float4*)(w1row + k0 + c4);
    const float4 b3v = *(const float4*)(w3row + k0 + c4);
    __syncthreads();
    As[c4 + 0][r] = av.x; As[c4 + 1][r] = av.y; As[c4 + 2][r] = av.z; As[c4 + 3][r] = av.w;
    B1[c4 + 0][r] = b1v.x; B1[c4 + 1][r] = b1v.y; B1[c4 + 2][r] = b1v.z; B1[c4 + 3][r] = b1v.w;
    B3[c4 + 0][r] = b3v.x; B3[c4 + 1][r] = b3v.y; B3[c4 + 2][r] = b3v.z; B3[c4 + 3][r] = b3v.w;
    __syncthreads();
#pragma unroll
    for (int k = 0; k < 16; k++) {
      const float4 a = *(const float4*)(&As[k][ty * 4]);
      const float4 b1f = *(const float4*)(&B1[k][tx * 4]);
      const float4 b3f = *(const float4*)(&B3[k][tx * 4]);
      const float am[4] = {a.x, a.y, a.z, a.w};
      const float b1a[4] = {b1f.x, b1f.y, b1f.z, b1f.w};
      const float b3a[4] = {b3f.x, b3f.y, b3f.z, b3f.w};
#pragma unroll
      for (int im = 0; im < 4; im++) {
#pragma unroll
        for (int in = 0; in < 4; in++) {
          acc1[im][in] = fmaf(am[im], b1a[in], acc1[im][in]);
          acc3[im][in] = fmaf(am[im], b3a[in], acc3[im][in]);
        }
      }
    }
  }

  const int colBase = n0 + tx * 4;
#pragma unroll
  for (int im = 0; im < 4; im++) {
    int p = p0 + ty * 4 + im;
    if (!ROUTED || p < realEnd) {
      float h0 = silu_f(acc1[im][0]) * acc3[im][0];
      float h1 = silu_f(acc1[im][1]) * acc3[im][1];
      float h2 = silu_f(acc1[im][2]) * acc3[im][2];
      float h3 = silu_f(acc1[im][3]) * acc3[im][3];
      ushort4 hv;
      hv.x = f2bf(h0); hv.y = f2bf(h1); hv.z = f2bf(h2); hv.w = f2bf(h3);
      *(ushort4*)(&H[(size_t)p * INTER + colBase]) = hv;
    }
  }
}

// ---------- GEMM 2: y = h @ w2^T; shared writes out, routed atomic-adds ----------
template <bool ROUTED>
__global__ __launch_bounds__(256) void out_kernel(
    const unsigned short* __restrict__ H, const float* __restrict__ w2all,
    const int* __restrict__ cnt, const int* __restrict__ pair_tok,
    const float* __restrict__ pair_w, float* __restrict__ out) {
  const int p0 = blockIdx.y * 64;
  int realEnd;
  const float* w2e;
  if (ROUTED) {
    int base = 0, eSel = -1; realEnd = 0;
    for (int i = 0; i < NE; i++) {
      int c = cnt[i];
      int pad = (c + 63) & ~63;
      if (eSel < 0) {
        if (p0 < base + pad) { eSel = i; realEnd = base + c; }
        else base += pad;
      }
    }
    if (eSel < 0 || p0 >= realEnd) return;
    w2e = w2all + (size_t)eSel * DIM * INTER;
  } else {
    realEnd = T_TOKENS;
    w2e = w2all;
  }

  const int tid = threadIdx.x;
  const int r = tid >> 2;
  const int c4 = (tid & 3) * 4;
  const int tx = tid & 15;
  const int ty = tid >> 4;
  const int n0 = blockIdx.x * 64;

  const unsigned short* Hrow = H + (size_t)(p0 + r) * INTER;
  const float* w2row = w2e + (size_t)(n0 + r) * INTER;

  __shared__ float As[16][64];
  __shared__ float Bs[16][64];

  float acc[4][4] = {};

  for (int k0 = 0; k0 < INTER; k0 += 16) {
    const ushort4 av = *(const ushort4*)(Hrow + k0 + c4);
    const float4 bv = *(const float4*)(w2row + k0 + c4);
    __syncthreads();
    As[c4 + 0][r] = bf2f(av.x); As[c4 + 1][r] = bf2f(av.y);
    As[c4 + 2][r] = bf2f(av.z); As[c4 + 3][r] = bf2f(av.w);
    Bs[c4 + 0][r] = bv.x; Bs[c4 + 1][r] = bv.y; Bs[c4 + 2][r] = bv.z; Bs[c4 + 3][r] = bv.w;
    __syncthreads();
#pragma unroll
    for (int k = 0; k < 16; k++) {
      const float4 a = *(const float4*)(&As[k][ty * 4]);
      const float4 b = *(const float4*)(&Bs[k][tx * 4]);
      const float am[4] = {a.x, a.y, a.z, a.w};
      const float bn[4] = {b.x, b.y, b.z, b.w};
#pragma unroll
      for (int im = 0; im < 4; im++) {
#pragma unroll
        for (int in = 0; in < 4; in++) {
          acc[im][in] = fmaf(am[im], bn[in], acc[im][in]);
        }
      }
    }
  }

#pragma unroll
  for (int im = 0; im < 4; im++) {
    int p = p0 + ty * 4 + im;
    if (ROUTED) {
      if (p < realEnd) {
        int tok = pair_tok[p];
        float wgt = pair_w[p];
        float* orow = out + (size_t)tok * DIM + n0 + tx * 4;
        atomicAdd(&orow[0], acc[im][0] * wgt);
        atomicAdd(&orow[1], acc[im][1] * wgt);
        atomicAdd(&orow[2], acc[im][2] * wgt);
        atomicAdd(&orow[3], acc[im][3] * wgt);
      }
    } else {
      float4 v = make_float4(acc[im][0], acc[im][1], acc[im][2], acc[im][3]);
      *(float4*)(out + (size_t)p * DIM + n0 + tx * 4) = v;
    }
  }
}

// ---------- launch ----------
extern "C" void kernel_launch(void* const* d_in, const int* in_sizes, int n_in,
                              void* d_out, int out_size, void* d_ws, size_t ws_size,
                              hipStream_t stream) {
  const float* x   = (const float*)d_in[0];
  const float* gw  = (const float*)d_in[1];
  const float* gb  = (const float*)d_in[2];
  const float* w1  = (const float*)d_in[3];
  const float* w2  = (const float*)d_in[4];
  const float* w3  = (const float*)d_in[5];
  const float* sw1 = (const float*)d_in[6];
  const float* sw2 = (const float*)d_in[7];
  const float* sw3 = (const float*)d_in[8];
  float* out = (float*)d_out;
  (void)in_sizes; (void)n_in; (void)out_size; (void)ws_size;

  char* ws = (char*)d_ws;
  int* cnt = (int*)ws;                       // 8
  int* fill = cnt + 8;                       // 8
  int* topk_idx = fill + 8;                  // 2T
  float* topk_w = (float*)(topk_idx + 2 * T_TOKENS);
  int* pair_tok = (int*)(topk_w + 2 * T_TOKENS);
  float* pair_w = (float*)(pair_tok + CAP);
  size_t used = (size_t)((char*)(pair_w + CAP) - ws);
  used = (used + 255) & ~(size_t)255;
  unsigned short* H = (unsigned short*)(ws + used);  // CAP x INTER bf16 (~66 MB)

  init_kernel<<<1, 64, 0, stream>>>(cnt, fill);
  gate_kernel<<<T_TOKENS / 4, 256, 0, stream>>>(x, gw, gb, cnt, topk_idx, topk_w);
  scatter_kernel<<<T_TOKENS / 256, 256, 0, stream>>>(cnt, fill, topk_idx, topk_w,
                                                     pair_tok, pair_w);
  // shared expert: h then out (out_kernel<false> fully initializes d_out)
  h_kernel<false><<<dim3(INTER / 64, T_TOKENS / 64), 256, 0, stream>>>(
      x, sw1, sw3, nullptr, nullptr, H);
  out_kernel<false><<<dim3(DIM / 64, T_TOKENS / 64), 256, 0, stream>>>(
      H, sw2, nullptr, nullptr, nullptr, out);
  // routed experts: gathered h then weighted atomic scatter-add
  h_kernel<true><<<dim3(INTER / 64, CAP / 64), 256, 0, stream>>>(
      x, w1, w3, cnt, pair_tok, H);
  out_kernel<true><<<dim3(DIM / 64, CAP / 64), 256, 0, stream>>>(
      H, w2, cnt, pair_tok, pair_w, out);
}

// Round 2
// 1247.825 us; speedup vs baseline: 3.5844x; 3.5844x over previous
//
#include <hip/hip_runtime.h>
#include <hip/hip_bf16.h>
#include <math.h>

#define T_TOKENS 8192
#define DIMK     1024
#define INTER    2048
#define NE       8
#define CAP      17408   // 2*T + NE*128 (per-expert 128-row padding)
#define BM 128
#define BN 128
#define BK 32
#define SA 40            // LDS row stride in shorts (32 + 8 pad)

typedef __attribute__((ext_vector_type(8))) short bf16x8;
typedef __attribute__((ext_vector_type(8))) unsigned short u16x8;
typedef __attribute__((ext_vector_type(4))) float f32x4;

__device__ __forceinline__ unsigned short f2bf(float f) {
  unsigned int u = __float_as_uint(f);
  unsigned int r = 0x7FFFu + ((u >> 16) & 1u);
  return (unsigned short)((u + r) >> 16);
}
__device__ __forceinline__ float silu_f(float v) { return v / (1.0f + expf(-v)); }

__device__ __forceinline__ u16x8 cvt8(float4 a, float4 b) {
  u16x8 r;
  r[0] = f2bf(a.x); r[1] = f2bf(a.y); r[2] = f2bf(a.z); r[3] = f2bf(a.w);
  r[4] = f2bf(b.x); r[5] = f2bf(b.y); r[6] = f2bf(b.z); r[7] = f2bf(b.w);
  return r;
}

// expert region lookup for 128-padded pair lists; true if this 128-row tile
// contains at least one valid row
__device__ __forceinline__ bool find_expert(const int* cnt, int p0, int& eSel,
                                            int& realEnd) {
  int base = 0;
  for (int i = 0; i < NE; i++) {
    int c = cnt[i];
    int pad = (c + 127) & ~127;
    if (p0 < base + pad) { eSel = i; realEnd = base + c; return p0 < base + c; }
    base += pad;
  }
  return false;
}

// ---------- init ----------
__global__ void init_kernel(int* __restrict__ cnt, int* __restrict__ fill) {
  int i = threadIdx.x;
  if (i < NE) { cnt[i] = 0; fill[i] = 0; }
}

// ---------- fp32 -> bf16 convert ----------
__global__ __launch_bounds__(256) void cvt_kernel(const float* __restrict__ s,
                                                  unsigned short* __restrict__ d,
                                                  int n) {
  int i = (blockIdx.x * 256 + threadIdx.x) * 8;
  if (i >= n) return;
  float4 a = *(const float4*)(s + i);
  float4 b = *(const float4*)(s + i + 4);
  *(u16x8*)(d + i) = cvt8(a, b);
}

// ---------- gate ----------
__global__ __launch_bounds__(256) void gate_kernel(
    const float* __restrict__ x, const float* __restrict__ gw,
    const float* __restrict__ gb, int* __restrict__ cnt,
    int* __restrict__ topk_idx, float* __restrict__ topk_w) {
  const int wave = threadIdx.x >> 6;
  const int lane = threadIdx.x & 63;
  const int t = blockIdx.x * 4 + wave;
  if (t >= T_TOKENS) return;
  const float* xt = x + (size_t)t * DIMK;

  float p[NE];
#pragma unroll
  for (int e = 0; e < NE; e++) p[e] = 0.0f;
  for (int d = lane; d < DIMK; d += 64) {
    float xv = xt[d];
#pragma unroll
    for (int e = 0; e < NE; e++) p[e] += xv * gw[e * DIMK + d];
  }
#pragma unroll
  for (int e = 0; e < NE; e++) {
#pragma unroll
    for (int off = 32; off > 0; off >>= 1) p[e] += __shfl_xor(p[e], off, 64);
  }
  if (lane == 0) {
    float m = p[0];
#pragma unroll
    for (int e = 1; e < NE; e++) m = fmaxf(m, p[e]);
    float s[NE]; float den = 0.0f;
#pragma unroll
    for (int e = 0; e < NE; e++) { s[e] = expf(p[e] - m); den += s[e]; }
    float inv = 1.0f / den;
    float sc[NE], bi[NE];
#pragma unroll
    for (int e = 0; e < NE; e++) { sc[e] = s[e] * inv; bi[e] = sc[e] + gb[e]; }
    int i0 = 0; float b0 = bi[0];
#pragma unroll
    for (int e = 1; e < NE; e++) if (bi[e] > b0) { b0 = bi[e]; i0 = e; }
    int i1 = -1; float b1 = -1e30f;
#pragma unroll
    for (int e = 0; e < NE; e++) if (e != i0 && bi[e] > b1) { b1 = bi[e]; i1 = e; }
    topk_idx[t * 2 + 0] = i0;
    topk_idx[t * 2 + 1] = i1;
    topk_w[t * 2 + 0] = sc[i0];
    topk_w[t * 2 + 1] = sc[i1];
    atomicAdd(&cnt[i0], 1);
    atomicAdd(&cnt[i1], 1);
  }
}

// ---------- scatter ----------
__global__ __launch_bounds__(256) void scatter_kernel(
    const int* __restrict__ cnt, int* __restrict__ fill,
    const int* __restrict__ topk_idx, const float* __restrict__ topk_w,
    int* __restrict__ pair_tok, float* __restrict__ pair_w) {
  int t = blockIdx.x * blockDim.x + threadIdx.x;
  if (t >= T_TOKENS) return;
  int offp[NE];
  int o = 0;
#pragma unroll
  for (int e = 0; e < NE; e++) { offp[e] = o; o += (cnt[e] + 127) & ~127; }
#pragma unroll
  for (int k = 0; k < 2; k++) {
    int e = topk_idx[t * 2 + k];
    int pos = atomicAdd(&fill[e], 1);
    int p = offp[e] + pos;
    pair_tok[p] = t;
    pair_w[p] = topk_w[t * 2 + k];
  }
}

// ---------- MFMA GEMM 1: H = silu(A@W1^T) * (A@W3^T), bf16 ----------
template <bool ROUTED, bool BBF16>
__global__ __launch_bounds__(256) void h_mfma(
    const unsigned short* __restrict__ xb, const void* __restrict__ w1p,
    const void* __restrict__ w3p, const int* __restrict__ cnt,
    const int* __restrict__ pair_tok, unsigned short* __restrict__ H) {
  const int p0 = blockIdx.y * BM;
  int realEnd = T_TOKENS, eSel = 0;
  if (ROUTED) {
    if (!find_expert(cnt, p0, eSel, realEnd)) return;
  }
  const size_t wOff = (size_t)eSel * INTER * DIMK;
  const unsigned short* w1b = nullptr; const unsigned short* w3b = nullptr;
  const float* w1f = nullptr; const float* w3f = nullptr;
  if constexpr (BBF16) {
    w1b = (const unsigned short*)w1p + wOff;
    w3b = (const unsigned short*)w3p + wOff;
  } else {
    w1f = (const float*)w1p + wOff;
    w3f = (const float*)w3p + wOff;
  }

  const int tid = threadIdx.x;
  const int lane = tid & 63;
  const int wv = tid >> 6;
  const int wm = (wv & 1) * 64, wn = (wv >> 1) * 64;
  const int lm = lane & 15, quad = lane >> 4;
  const int n0 = blockIdx.x * BN;

  const int srow = tid >> 1;
  const int skh = (tid & 1) * 16;

  int arow = p0 + srow;
  int tokr;
  if (ROUTED) tokr = pair_tok[arow < realEnd ? arow : realEnd - 1];
  else tokr = arow;
  const unsigned short* aptr = xb + (size_t)tokr * DIMK + skh;

  const unsigned short* b1pb = nullptr; const unsigned short* b3pb = nullptr;
  const float* b1pf = nullptr; const float* b3pf = nullptr;
  if constexpr (BBF16) {
    b1pb = w1b + (size_t)(n0 + srow) * DIMK + skh;
    b3pb = w3b + (size_t)(n0 + srow) * DIMK + skh;
  } else {
    b1pf = w1f + (size_t)(n0 + srow) * DIMK + skh;
    b3pf = w3f + (size_t)(n0 + srow) * DIMK + skh;
  }

  __shared__ unsigned short As[BM * SA];
  __shared__ unsigned short B1s[BN * SA];
  __shared__ unsigned short B3s[BN * SA];
  const int wbase = srow * SA + skh;

  f32x4 acc1[4][4] = {};
  f32x4 acc3[4][4] = {};

  for (int k0 = 0; k0 < DIMK; k0 += BK) {
    u16x8 av0, av1, b1v0, b1v1, b3v0, b3v1;
    av0 = *(const u16x8*)(aptr + k0);
    av1 = *(const u16x8*)(aptr + k0 + 8);
    if constexpr (BBF16) {
      b1v0 = *(const u16x8*)(b1pb + k0);
      b1v1 = *(const u16x8*)(b1pb + k0 + 8);
      b3v0 = *(const u16x8*)(b3pb + k0);
      b3v1 = *(const u16x8*)(b3pb + k0 + 8);
    } else {
      const float4* bp1 = (const float4*)(b1pf + k0);
      const float4* bp3 = (const float4*)(b3pf + k0);
      b1v0 = cvt8(bp1[0], bp1[1]); b1v1 = cvt8(bp1[2], bp1[3]);
      b3v0 = cvt8(bp3[0], bp3[1]); b3v1 = cvt8(bp3[2], bp3[3]);
    }
    __syncthreads();
    *(u16x8*)&As[wbase] = av0;  *(u16x8*)&As[wbase + 8] = av1;
    *(u16x8*)&B1s[wbase] = b1v0; *(u16x8*)&B1s[wbase + 8] = b1v1;
    *(u16x8*)&B3s[wbase] = b3v0; *(u16x8*)&B3s[wbase + 8] = b3v1;
    __syncthreads();

    bf16x8 af[4], b1f[4], b3f[4];
#pragma unroll
    for (int mi = 0; mi < 4; mi++)
      af[mi] = *(const bf16x8*)&As[(wm + mi * 16 + lm) * SA + quad * 8];
#pragma unroll
    for (int ni = 0; ni < 4; ni++) {
      b1f[ni] = *(const bf16x8*)&B1s[(wn + ni * 16 + lm) * SA + quad * 8];
      b3f[ni] = *(const bf16x8*)&B3s[(wn + ni * 16 + lm) * SA + quad * 8];
    }
#pragma unroll
    for (int mi = 0; mi < 4; mi++) {
#pragma unroll
      for (int ni = 0; ni < 4; ni++) {
        acc1[mi][ni] = __builtin_amdgcn_mfma_f32_16x16x32_bf16(
            af[mi], b1f[ni], acc1[mi][ni], 0, 0, 0);
        acc3[mi][ni] = __builtin_amdgcn_mfma_f32_16x16x32_bf16(
            af[mi], b3f[ni], acc3[mi][ni], 0, 0, 0);
      }
    }
  }

  const int colBase = n0 + wn + lm;
#pragma unroll
  for (int mi = 0; mi < 4; mi++) {
#pragma unroll
    for (int r = 0; r < 4; r++) {
      int row = p0 + wm + mi * 16 + quad * 4 + r;
      if (!ROUTED || row < realEnd) {
        unsigned short* hrow = H + (size_t)row * INTER;
#pragma unroll
        for (int ni = 0; ni < 4; ni++) {
          float v = silu_f(acc1[mi][ni][r]) * acc3[mi][ni][r];
          hrow[colBase + ni * 16] = f2bf(v);
        }
      }
    }
  }
}

// ---------- MFMA GEMM 2: out = H @ W2^T ----------
template <bool ROUTED, bool BBF16>
__global__ __launch_bounds__(256) void out_mfma(
    const unsigned short* __restrict__ H, const void* __restrict__ w2p,
    const int* __restrict__ cnt, const int* __restrict__ pair_tok,
    const float* __restrict__ pair_w, float* __restrict__ out) {
  const int p0 = blockIdx.y * BM;
  int realEnd = T_TOKENS, eSel = 0;
  if (ROUTED) {
    if (!find_expert(cnt, p0, eSel, realEnd)) return;
  }
  const size_t wOff = (size_t)eSel * DIMK * INTER;
  const unsigned short* w2b = nullptr; const float* w2f = nullptr;
  if constexpr (BBF16) w2b = (const unsigned short*)w2p + wOff;
  else w2f = (const float*)w2p + wOff;

  const int tid = threadIdx.x;
  const int lane = tid & 63;
  const int wv = tid >> 6;
  const int wm = (wv & 1) * 64, wn = (wv >> 1) * 64;
  const int lm = lane & 15, quad = lane >> 4;
  const int n0 = blockIdx.x * BN;

  const int srow = tid >> 1;
  const int skh = (tid & 1) * 16;

  const unsigned short* aptr = H + (size_t)(p0 + srow) * INTER + skh;
  const unsigned short* bpb = nullptr; const float* bpf = nullptr;
  if constexpr (BBF16) bpb = w2b + (size_t)(n0 + srow) * INTER + skh;
  else bpf = w2f + (size_t)(n0 + srow) * INTER + skh;

  __shared__ unsigned short As[BM * SA];
  __shared__ unsigned short Bs[BN * SA];
  const int wbase = srow * SA + skh;

  f32x4 acc[4][4] = {};

  for (int k0 = 0; k0 < INTER; k0 += BK) {
    u16x8 av0 = *(const u16x8*)(aptr + k0);
    u16x8 av1 = *(const u16x8*)(aptr + k0 + 8);
    u16x8 bv0, bv1;
    if constexpr (BBF16) {
      bv0 = *(const u16x8*)(bpb + k0);
      bv1 = *(const u16x8*)(bpb + k0 + 8);
    } else {
      const float4* bp = (const float4*)(bpf + k0);
      bv0 = cvt8(bp[0], bp[1]); bv1 = cvt8(bp[2], bp[3]);
    }
    __syncthreads();
    *(u16x8*)&As[wbase] = av0; *(u16x8*)&As[wbase + 8] = av1;
    *(u16x8*)&Bs[wbase] = bv0; *(u16x8*)&Bs[wbase + 8] = bv1;
    __syncthreads();

    bf16x8 af[4], bf[4];
#pragma unroll
    for (int mi = 0; mi < 4; mi++)
      af[mi] = *(const bf16x8*)&As[(wm + mi * 16 + lm) * SA + quad * 8];
#pragma unroll
    for (int ni = 0; ni < 4; ni++)
      bf[ni] = *(const bf16x8*)&Bs[(wn + ni * 16 + lm) * SA + quad * 8];
#pragma unroll
    for (int mi = 0; mi < 4; mi++) {
#pragma unroll
      for (int ni = 0; ni < 4; ni++) {
        acc[mi][ni] = __builtin_amdgcn_mfma_f32_16x16x32_bf16(
            af[mi], bf[ni], acc[mi][ni], 0, 0, 0);
      }
    }
  }

  const int colBase = n0 + wn + lm;
#pragma unroll
  for (int mi = 0; mi < 4; mi++) {
#pragma unroll
    for (int r = 0; r < 4; r++) {
      int row = p0 + wm + mi * 16 + quad * 4 + r;
      if (ROUTED) {
        if (row < realEnd) {
          int tok = pair_tok[row];
          float wgt = pair_w[row];
          float* orow = out + (size_t)tok * DIMK;
#pragma unroll
          for (int ni = 0; ni < 4; ni++)
            atomicAdd(&orow[colBase + ni * 16], acc[mi][ni][r] * wgt);
        }
      } else {
        float* orow = out + (size_t)row * DIMK;
#pragma unroll
        for (int ni = 0; ni < 4; ni++)
          orow[colBase + ni * 16] = acc[mi][ni][r];
      }
    }
  }
}

// ---------- launch ----------
extern "C" void kernel_launch(void* const* d_in, const int* in_sizes, int n_in,
                              void* d_out, int out_size, void* d_ws, size_t ws_size,
                              hipStream_t stream) {
  const float* x   = (const float*)d_in[0];
  const float* gw  = (const float*)d_in[1];
  const float* gb  = (const float*)d_in[2];
  const float* w1  = (const float*)d_in[3];
  const float* w2  = (const float*)d_in[4];
  const float* w3  = (const float*)d_in[5];
  const float* sw1 = (const float*)d_in[6];
  const float* sw2 = (const float*)d_in[7];
  const float* sw3 = (const float*)d_in[8];
  float* out = (float*)d_out;
  (void)in_sizes; (void)n_in; (void)out_size;

  char* ws = (char*)d_ws;
  int* cnt = (int*)ws;
  int* fill = cnt + 8;
  int* topk_idx = fill + 8;
  float* topk_w = (float*)(topk_idx + 2 * T_TOKENS);
  int* pair_tok = (int*)(topk_w + 2 * T_TOKENS);
  float* pair_w = (float*)(pair_tok + CAP);
  size_t off = (size_t)((char*)(pair_w + CAP) - ws);
  off = (off + 255) & ~(size_t)255;
  unsigned short* H = (unsigned short*)(ws + off);
  off += (size_t)CAP * INTER * 2;
  unsigned short* xb = (unsigned short*)(ws + off);
  off += (size_t)T_TOKENS * DIMK * 2;

  const int nW1 = NE * INTER * DIMK;        // 16.8M elements
  const int nSW = INTER * DIMK;             // 2.1M elements
  size_t wNeed = ((size_t)nW1 * 3 + (size_t)nSW * 3) * 2;
  const bool PRE = (ws_size >= off + wNeed);

  unsigned short *w1b = nullptr, *w3b = nullptr, *w2b = nullptr;
  unsigned short *sw1b = nullptr, *sw3b = nullptr, *sw2b = nullptr;
  if (PRE) {
    w1b = (unsigned short*)(ws + off); off += (size_t)nW1 * 2;
    w3b = (unsigned short*)(ws + off); off += (size_t)nW1 * 2;
    w2b = (unsigned short*)(ws + off); off += (size_t)nW1 * 2;
    sw1b = (unsigned short*)(ws + off); off += (size_t)nSW * 2;
    sw3b = (unsigned short*)(ws + off); off += (size_t)nSW * 2;
    sw2b = (unsigned short*)(ws + off); off += (size_t)nSW * 2;
  }

  init_kernel<<<1, 64, 0, stream>>>(cnt, fill);
  cvt_kernel<<<(T_TOKENS * DIMK) / 2048, 256, 0, stream>>>(x, xb, T_TOKENS * DIMK);
  if (PRE) {
    cvt_kernel<<<nW1 / 2048, 256, 0, stream>>>(w1, w1b, nW1);
    cvt_kernel<<<nW1 / 2048, 256, 0, stream>>>(w3, w3b, nW1);
    cvt_kernel<<<nW1 / 2048, 256, 0, stream>>>(w2, w2b, nW1);
    cvt_kernel<<<nSW / 2048, 256, 0, stream>>>(sw1, sw1b, nSW);
    cvt_kernel<<<nSW / 2048, 256, 0, stream>>>(sw3, sw3b, nSW);
    cvt_kernel<<<nSW / 2048, 256, 0, stream>>>(sw2, sw2b, nSW);
  }
  gate_kernel<<<T_TOKENS / 4, 256, 0, stream>>>(x, gw, gb, cnt, topk_idx, topk_w);
  scatter_kernel<<<T_TOKENS / 256, 256, 0, stream>>>(cnt, fill, topk_idx, topk_w,
                                                     pair_tok, pair_w);
  if (PRE) {
    h_mfma<false, true><<<dim3(INTER / BN, T_TOKENS / BM), 256, 0, stream>>>(
        xb, sw1b, sw3b, nullptr, nullptr, H);
    out_mfma<false, true><<<dim3(DIMK / BN, T_TOKENS / BM), 256, 0, stream>>>(
        H, sw2b, nullptr, nullptr, nullptr, out);
    h_mfma<true, true><<<dim3(INTER / BN, CAP / BM), 256, 0, stream>>>(
        xb, w1b, w3b, cnt, pair_tok, H);
    out_mfma<true, true><<<dim3(DIMK / BN, CAP / BM), 256, 0, stream>>>(
        H, w2b, cnt, pair_tok, pair_w, out);
  } else {
    h_mfma<false, false><<<dim3(INTER / BN, T_TOKENS / BM), 256, 0, stream>>>(
        xb, sw1, sw3, nullptr, nullptr, H);
    out_mfma<false, false><<<dim3(DIMK / BN, T_TOKENS / BM), 256, 0, stream>>>(
        H, sw2, nullptr, nullptr, nullptr, out);
    h_mfma<true, false><<<dim3(INTER / BN, CAP / BM), 256, 0, stream>>>(
        xb, w1, w3, cnt, pair_tok, H);
    out_mfma<true, false><<<dim3(DIMK / BN, CAP / BM), 256, 0, stream>>>(
        H, w2, cnt, pair_tok, pair_w, out);
  }
}

// Round 3
// 1066.424 us; speedup vs baseline: 4.1942x; 1.1701x over previous
//
#include <hip/hip_runtime.h>
#include <hip/hip_bf16.h>
#include <math.h>

#define T_TOKENS 8192
#define DIMK     1024
#define INTER    2048
#define NE       8
#define CAP      17408   // 2*T + NE*128

typedef __attribute__((ext_vector_type(8))) short bf16x8;
typedef __attribute__((ext_vector_type(8))) unsigned short u16x8;
typedef __attribute__((ext_vector_type(4))) float f32x4;

__device__ __forceinline__ unsigned short f2bf(float f) {
  unsigned int u = __float_as_uint(f);
  unsigned int r = 0x7FFFu + ((u >> 16) & 1u);
  return (unsigned short)((u + r) >> 16);
}
__device__ __forceinline__ float silu_f(float v) { return v / (1.0f + expf(-v)); }

__device__ __forceinline__ u16x8 cvt8(float4 a, float4 b) {
  u16x8 r;
  r[0] = f2bf(a.x); r[1] = f2bf(a.y); r[2] = f2bf(a.z); r[3] = f2bf(a.w);
  r[4] = f2bf(b.x); r[5] = f2bf(b.y); r[6] = f2bf(b.z); r[7] = f2bf(b.w);
  return r;
}

// async global->LDS, 16B per lane. LDS dest must be wave-uniform base + lane*16.
__device__ __forceinline__ void gl_lds16(const void* g, void* l) {
  __builtin_amdgcn_global_load_lds(
      (const __attribute__((address_space(1))) void*)g,
      (__attribute__((address_space(3))) void*)l, 16, 0, 0);
}

__device__ __forceinline__ bool find_expert(const int* cnt, int p0, int& eSel,
                                            int& realEnd) {
  int base = 0;
  for (int i = 0; i < NE; i++) {
    int c = cnt[i];
    int pad = (c + 127) & ~127;
    if (p0 < base + pad) { eSel = i; realEnd = base + c; return p0 < base + c; }
    base += pad;
  }
  return false;
}

// ---------- init ----------
__global__ void init_kernel(int* __restrict__ cnt, int* __restrict__ fill) {
  int i = threadIdx.x;
  if (i < NE) { cnt[i] = 0; fill[i] = 0; }
}

// ---------- fp32 -> bf16 ----------
__global__ __launch_bounds__(256) void cvt_kernel(const float* __restrict__ s,
                                                  unsigned short* __restrict__ d,
                                                  int n) {
  int i = (blockIdx.x * 256 + threadIdx.x) * 8;
  if (i >= n) return;
  float4 a = *(const float4*)(s + i);
  float4 b = *(const float4*)(s + i + 4);
  *(u16x8*)(d + i) = cvt8(a, b);
}

// ---------- gate ----------
__global__ __launch_bounds__(256) void gate_kernel(
    const float* __restrict__ x, const float* __restrict__ gw,
    const float* __restrict__ gb, int* __restrict__ cnt,
    int* __restrict__ topk_idx, float* __restrict__ topk_w) {
  const int wave = threadIdx.x >> 6;
  const int lane = threadIdx.x & 63;
  const int t = blockIdx.x * 4 + wave;
  if (t >= T_TOKENS) return;
  const float* xt = x + (size_t)t * DIMK;

  float p[NE];
#pragma unroll
  for (int e = 0; e < NE; e++) p[e] = 0.0f;
  for (int d = lane; d < DIMK; d += 64) {
    float xv = xt[d];
#pragma unroll
    for (int e = 0; e < NE; e++) p[e] += xv * gw[e * DIMK + d];
  }
#pragma unroll
  for (int e = 0; e < NE; e++) {
#pragma unroll
    for (int off = 32; off > 0; off >>= 1) p[e] += __shfl_xor(p[e], off, 64);
  }
  if (lane == 0) {
    float m = p[0];
#pragma unroll
    for (int e = 1; e < NE; e++) m = fmaxf(m, p[e]);
    float s[NE]; float den = 0.0f;
#pragma unroll
    for (int e = 0; e < NE; e++) { s[e] = expf(p[e] - m); den += s[e]; }
    float inv = 1.0f / den;
    float sc[NE], bi[NE];
#pragma unroll
    for (int e = 0; e < NE; e++) { sc[e] = s[e] * inv; bi[e] = sc[e] + gb[e]; }
    int i0 = 0; float b0 = bi[0];
#pragma unroll
    for (int e = 1; e < NE; e++) if (bi[e] > b0) { b0 = bi[e]; i0 = e; }
    int i1 = -1; float b1 = -1e30f;
#pragma unroll
    for (int e = 0; e < NE; e++) if (e != i0 && bi[e] > b1) { b1 = bi[e]; i1 = e; }
    topk_idx[t * 2 + 0] = i0;
    topk_idx[t * 2 + 1] = i1;
    topk_w[t * 2 + 0] = sc[i0];
    topk_w[t * 2 + 1] = sc[i1];
    atomicAdd(&cnt[i0], 1);
    atomicAdd(&cnt[i1], 1);
  }
}

// ---------- scatter ----------
__global__ __launch_bounds__(256) void scatter_kernel(
    const int* __restrict__ cnt, int* __restrict__ fill,
    const int* __restrict__ topk_idx, const float* __restrict__ topk_w,
    int* __restrict__ pair_tok, float* __restrict__ pair_w) {
  int t = blockIdx.x * blockDim.x + threadIdx.x;
  if (t >= T_TOKENS) return;
  int offp[NE];
  int o = 0;
#pragma unroll
  for (int e = 0; e < NE; e++) { offp[e] = o; o += (cnt[e] + 127) & ~127; }
#pragma unroll
  for (int k = 0; k < 2; k++) {
    int e = topk_idx[t * 2 + k];
    int pos = atomicAdd(&fill[e], 1);
    int p = offp[e] + pos;
    pair_tok[p] = t;
    pair_w[p] = topk_w[t * 2 + k];
  }
}

// ---------- GEMM 1: H = silu(A@W1^T)*(A@W3^T) ----------
// block tile: 128M x 64N; 4 waves, each 64M x 32N per matrix (acc 64 AGPR)
template <bool ROUTED, bool BBF16>
__global__ __launch_bounds__(256) void h_mfma(
    const unsigned short* __restrict__ xb, const void* __restrict__ w1p,
    const void* __restrict__ w3p, const int* __restrict__ cnt,
    const int* __restrict__ pair_tok, unsigned short* __restrict__ H) {
  const int p0 = blockIdx.y * 128;
  int realEnd = T_TOKENS, eSel = 0;
  if (ROUTED) {
    if (!find_expert(cnt, p0, eSel, realEnd)) return;
  }
  const size_t wOff = (size_t)eSel * INTER * DIMK;

  const int tid = threadIdx.x;
  const int lane = tid & 63;
  const int wv = tid >> 6;
  const int wm = (wv & 1) * 64, wn = (wv >> 1) * 32;
  const int lm = lane & 15, quad = lane >> 4;
  const int n0 = blockIdx.x * 64;

  // staging coords: row = tid>>2 (0..63), kgroup = (tid&3)*8 shorts
  const int srow = tid >> 2;
  const int skg = (tid & 3) * 8;

  // A rows (two rounds: srow, srow+64)
  int pa0 = p0 + srow, pa1 = p0 + srow + 64;
  int tok0, tok1;
  if (ROUTED) {
    tok0 = pair_tok[pa0 < realEnd ? pa0 : realEnd - 1];
    tok1 = pair_tok[pa1 < realEnd ? pa1 : realEnd - 1];
  } else { tok0 = pa0; tok1 = pa1; }
  const unsigned short* aSrc0 = xb + (size_t)tok0 * DIMK + skg;
  const unsigned short* aSrc1 = xb + (size_t)tok1 * DIMK + skg;

  const unsigned short* b1Src = nullptr; const unsigned short* b3Src = nullptr;
  const float* b1f32 = nullptr; const float* b3f32 = nullptr;
  if constexpr (BBF16) {
    b1Src = (const unsigned short*)w1p + wOff + (size_t)(n0 + srow) * DIMK + skg;
    b3Src = (const unsigned short*)w3p + wOff + (size_t)(n0 + srow) * DIMK + skg;
  } else {
    b1f32 = (const float*)w1p + wOff + (size_t)(n0 + srow) * DIMK + skg;
    b3f32 = (const float*)w3p + wOff + (size_t)(n0 + srow) * DIMK + skg;
  }

  __shared__ unsigned short As[128 * 32];   // 8 KB
  __shared__ unsigned short B1s[64 * 32];   // 4 KB
  __shared__ unsigned short B3s[64 * 32];   // 4 KB

  f32x4 acc1[4][2] = {};
  f32x4 acc3[4][2] = {};

  for (int k0 = 0; k0 < DIMK; k0 += 32) {
    u16x8 b1v, b3v;
    if constexpr (!BBF16) {
      const float4* p1 = (const float4*)(b1f32 + k0);
      const float4* p3 = (const float4*)(b3f32 + k0);
      float4 a1 = p1[0], b1 = p1[1], a3 = p3[0], b3 = p3[1];
      b1v = cvt8(a1, b1);
      b3v = cvt8(a3, b3);
    }
    __syncthreads();
    gl_lds16(aSrc0 + k0, As + tid * 8);
    gl_lds16(aSrc1 + k0, As + 2048 + tid * 8);
    if constexpr (BBF16) {
      gl_lds16(b1Src + k0, B1s + tid * 8);
      gl_lds16(b3Src + k0, B3s + tid * 8);
    } else {
      *(u16x8*)(B1s + tid * 8) = b1v;
      *(u16x8*)(B3s + tid * 8) = b3v;
    }
    __syncthreads();

    bf16x8 af[4], b1r[2], b3r[2];
#pragma unroll
    for (int mi = 0; mi < 4; mi++)
      af[mi] = *(const bf16x8*)&As[(wm + mi * 16 + lm) * 32 + quad * 8];
#pragma unroll
    for (int ni = 0; ni < 2; ni++) {
      b1r[ni] = *(const bf16x8*)&B1s[(wn + ni * 16 + lm) * 32 + quad * 8];
      b3r[ni] = *(const bf16x8*)&B3s[(wn + ni * 16 + lm) * 32 + quad * 8];
    }
#pragma unroll
    for (int mi = 0; mi < 4; mi++) {
#pragma unroll
      for (int ni = 0; ni < 2; ni++) {
        acc1[mi][ni] = __builtin_amdgcn_mfma_f32_16x16x32_bf16(
            af[mi], b1r[ni], acc1[mi][ni], 0, 0, 0);
        acc3[mi][ni] = __builtin_amdgcn_mfma_f32_16x16x32_bf16(
            af[mi], b3r[ni], acc3[mi][ni], 0, 0, 0);
      }
    }
  }

#pragma unroll
  for (int mi = 0; mi < 4; mi++) {
#pragma unroll
    for (int r = 0; r < 4; r++) {
      int row = p0 + wm + mi * 16 + quad * 4 + r;
      if (!ROUTED || row < realEnd) {
        unsigned short* hrow = H + (size_t)row * INTER + n0 + wn + lm;
#pragma unroll
        for (int ni = 0; ni < 2; ni++) {
          float v = silu_f(acc1[mi][ni][r]) * acc3[mi][ni][r];
          hrow[ni * 16] = f2bf(v);
        }
      }
    }
  }
}

// ---------- GEMM 2: out = H @ W2^T (m97 tile: 128x128, 64x64/wave) ----------
template <bool ROUTED, bool BBF16>
__global__ __launch_bounds__(256) void out_mfma(
    const unsigned short* __restrict__ H, const void* __restrict__ w2p,
    const int* __restrict__ cnt, const int* __restrict__ pair_tok,
    const float* __restrict__ pair_w, float* __restrict__ out) {
  const int p0 = blockIdx.y * 128;
  int realEnd = T_TOKENS, eSel = 0;
  if (ROUTED) {
    if (!find_expert(cnt, p0, eSel, realEnd)) return;
  }
  const size_t wOff = (size_t)eSel * DIMK * INTER;

  const int tid = threadIdx.x;
  const int lane = tid & 63;
  const int wv = tid >> 6;
  const int wm = (wv & 1) * 64, wn = (wv >> 1) * 64;
  const int lm = lane & 15, quad = lane >> 4;
  const int n0 = blockIdx.x * 128;

  const int srow = tid >> 2;
  const int skg = (tid & 3) * 8;

  const unsigned short* aSrc0 = H + (size_t)(p0 + srow) * INTER + skg;
  const unsigned short* aSrc1 = H + (size_t)(p0 + srow + 64) * INTER + skg;

  const unsigned short* bSrc0 = nullptr; const unsigned short* bSrc1 = nullptr;
  const float* bF0 = nullptr; const float* bF1 = nullptr;
  if constexpr (BBF16) {
    bSrc0 = (const unsigned short*)w2p + wOff + (size_t)(n0 + srow) * INTER + skg;
    bSrc1 = (const unsigned short*)w2p + wOff + (size_t)(n0 + srow + 64) * INTER + skg;
  } else {
    bF0 = (const float*)w2p + wOff + (size_t)(n0 + srow) * INTER + skg;
    bF1 = (const float*)w2p + wOff + (size_t)(n0 + srow + 64) * INTER + skg;
  }

  __shared__ unsigned short As[128 * 32];  // 8 KB
  __shared__ unsigned short Bs[128 * 32];  // 8 KB

  f32x4 acc[4][4] = {};

  for (int k0 = 0; k0 < INTER; k0 += 32) {
    u16x8 bv0, bv1;
    if constexpr (!BBF16) {
      const float4* q0 = (const float4*)(bF0 + k0);
      const float4* q1 = (const float4*)(bF1 + k0);
      float4 a0 = q0[0], c0 = q0[1], a1 = q1[0], c1 = q1[1];
      bv0 = cvt8(a0, c0);
      bv1 = cvt8(a1, c1);
    }
    __syncthreads();
    gl_lds16(aSrc0 + k0, As + tid * 8);
    gl_lds16(aSrc1 + k0, As + 2048 + tid * 8);
    if constexpr (BBF16) {
      gl_lds16(bSrc0 + k0, Bs + tid * 8);
      gl_lds16(bSrc1 + k0, Bs + 2048 + tid * 8);
    } else {
      *(u16x8*)(Bs + tid * 8) = bv0;
      *(u16x8*)(Bs + 2048 + tid * 8) = bv1;
    }
    __syncthreads();

    bf16x8 af[4], bf[4];
#pragma unroll
    for (int mi = 0; mi < 4; mi++)
      af[mi] = *(const bf16x8*)&As[(wm + mi * 16 + lm) * 32 + quad * 8];
#pragma unroll
    for (int ni = 0; ni < 4; ni++)
      bf[ni] = *(const bf16x8*)&Bs[(wn + ni * 16 + lm) * 32 + quad * 8];
#pragma unroll
    for (int mi = 0; mi < 4; mi++) {
#pragma unroll
      for (int ni = 0; ni < 4; ni++) {
        acc[mi][ni] = __builtin_amdgcn_mfma_f32_16x16x32_bf16(
            af[mi], bf[ni], acc[mi][ni], 0, 0, 0);
      }
    }
  }

#pragma unroll
  for (int mi = 0; mi < 4; mi++) {
#pragma unroll
    for (int r = 0; r < 4; r++) {
      int row = p0 + wm + mi * 16 + quad * 4 + r;
      if (ROUTED) {
        if (row < realEnd) {
          int tok = pair_tok[row];
          float wgt = pair_w[row];
          float* orow = out + (size_t)tok * DIMK + n0 + wn + lm;
#pragma unroll
          for (int ni = 0; ni < 4; ni++)
            atomicAdd(&orow[ni * 16], acc[mi][ni][r] * wgt);
        }
      } else {
        float* orow = out + (size_t)row * DIMK + n0 + wn + lm;
#pragma unroll
        for (int ni = 0; ni < 4; ni++)
          orow[ni * 16] = acc[mi][ni][r];
      }
    }
  }
}

// ---------- launch ----------
extern "C" void kernel_launch(void* const* d_in, const int* in_sizes, int n_in,
                              void* d_out, int out_size, void* d_ws, size_t ws_size,
                              hipStream_t stream) {
  const float* x   = (const float*)d_in[0];
  const float* gw  = (const float*)d_in[1];
  const float* gb  = (const float*)d_in[2];
  const float* w1  = (const float*)d_in[3];
  const float* w2  = (const float*)d_in[4];
  const float* w3  = (const float*)d_in[5];
  const float* sw1 = (const float*)d_in[6];
  const float* sw2 = (const float*)d_in[7];
  const float* sw3 = (const float*)d_in[8];
  float* out = (float*)d_out;
  (void)in_sizes; (void)n_in; (void)out_size;

  char* ws = (char*)d_ws;
  int* cnt = (int*)ws;
  int* fill = cnt + 8;
  int* topk_idx = fill + 8;
  float* topk_w = (float*)(topk_idx + 2 * T_TOKENS);
  int* pair_tok = (int*)(topk_w + 2 * T_TOKENS);
  float* pair_w = (float*)(pair_tok + CAP);
  size_t off = (size_t)((char*)(pair_w + CAP) - ws);
  off = (off + 255) & ~(size_t)255;
  unsigned short* H = (unsigned short*)(ws + off);
  off += (size_t)CAP * INTER * 2;
  unsigned short* xb = (unsigned short*)(ws + off);
  off += (size_t)T_TOKENS * DIMK * 2;

  const int nW1 = NE * INTER * DIMK;
  const int nSW = INTER * DIMK;
  size_t wNeed = ((size_t)nW1 * 3 + (size_t)nSW * 3) * 2;
  const bool PRE = (ws_size >= off + wNeed);

  unsigned short *w1b = nullptr, *w3b = nullptr, *w2b = nullptr;
  unsigned short *sw1b = nullptr, *sw3b = nullptr, *sw2b = nullptr;
  if (PRE) {
    w1b = (unsigned short*)(ws + off); off += (size_t)nW1 * 2;
    w3b = (unsigned short*)(ws + off); off += (size_t)nW1 * 2;
    w2b = (unsigned short*)(ws + off); off += (size_t)nW1 * 2;
    sw1b = (unsigned short*)(ws + off); off += (size_t)nSW * 2;
    sw3b = (unsigned short*)(ws + off); off += (size_t)nSW * 2;
    sw2b = (unsigned short*)(ws + off); off += (size_t)nSW * 2;
  }

  init_kernel<<<1, 64, 0, stream>>>(cnt, fill);
  cvt_kernel<<<(T_TOKENS * DIMK) / 2048, 256, 0, stream>>>(x, xb, T_TOKENS * DIMK);
  if (PRE) {
    cvt_kernel<<<nW1 / 2048, 256, 0, stream>>>(w1, w1b, nW1);
    cvt_kernel<<<nW1 / 2048, 256, 0, stream>>>(w3, w3b, nW1);
    cvt_kernel<<<nW1 / 2048, 256, 0, stream>>>(w2, w2b, nW1);
    cvt_kernel<<<nSW / 2048, 256, 0, stream>>>(sw1, sw1b, nSW);
    cvt_kernel<<<nSW / 2048, 256, 0, stream>>>(sw3, sw3b, nSW);
    cvt_kernel<<<nSW / 2048, 256, 0, stream>>>(sw2, sw2b, nSW);
  }
  gate_kernel<<<T_TOKENS / 4, 256, 0, stream>>>(x, gw, gb, cnt, topk_idx, topk_w);
  scatter_kernel<<<T_TOKENS / 256, 256, 0, stream>>>(cnt, fill, topk_idx, topk_w,
                                                     pair_tok, pair_w);
  if (PRE) {
    h_mfma<false, true><<<dim3(INTER / 64, T_TOKENS / 128), 256, 0, stream>>>(
        xb, sw1b, sw3b, nullptr, nullptr, H);
    out_mfma<false, true><<<dim3(DIMK / 128, T_TOKENS / 128), 256, 0, stream>>>(
        H, sw2b, nullptr, nullptr, nullptr, out);
    h_mfma<true, true><<<dim3(INTER / 64, CAP / 128), 256, 0, stream>>>(
        xb, w1b, w3b, cnt, pair_tok, H);
    out_mfma<true, true><<<dim3(DIMK / 128, CAP / 128), 256, 0, stream>>>(
        H, w2b, cnt, pair_tok, pair_w, out);
  } else {
    h_mfma<false, false><<<dim3(INTER / 64, T_TOKENS / 128), 256, 0, stream>>>(
        xb, sw1, sw3, nullptr, nullptr, H);
    out_mfma<false, false><<<dim3(DIMK / 128, T_TOKENS / 128), 256, 0, stream>>>(
        H, sw2, nullptr, nullptr, nullptr, out);
    h_mfma<true, false><<<dim3(INTER / 64, CAP / 128), 256, 0, stream>>>(
        xb, w1, w3, cnt, pair_tok, H);
    out_mfma<true, false><<<dim3(DIMK / 128, CAP / 128), 256, 0, stream>>>(
        H, w2, cnt, pair_tok, pair_w, out);
  }
}

// Round 4
// 1042.504 us; speedup vs baseline: 4.2904x; 1.0229x over previous
//
#include <hip/hip_runtime.h>
#include <hip/hip_bf16.h>
#include <math.h>

#define T_TOKENS 8192
#define DIMK     1024
#define INTER    2048
#define NE       8
#define CAP      17408   // 2*T + NE*128

typedef __attribute__((ext_vector_type(8))) short bf16x8;
typedef __attribute__((ext_vector_type(8))) unsigned short u16x8;
typedef __attribute__((ext_vector_type(4))) float f32x4;

__device__ __forceinline__ unsigned short f2bf(float f) {
  unsigned int u = __float_as_uint(f);
  unsigned int r = 0x7FFFu + ((u >> 16) & 1u);
  return (unsigned short)((u + r) >> 16);
}
__device__ __forceinline__ float silu_f(float v) { return v / (1.0f + expf(-v)); }

__device__ __forceinline__ u16x8 cvt8(float4 a, float4 b) {
  u16x8 r;
  r[0] = f2bf(a.x); r[1] = f2bf(a.y); r[2] = f2bf(a.z); r[3] = f2bf(a.w);
  r[4] = f2bf(b.x); r[5] = f2bf(b.y); r[6] = f2bf(b.z); r[7] = f2bf(b.w);
  return r;
}

__device__ __forceinline__ void gl_lds16(const void* g, void* l) {
  __builtin_amdgcn_global_load_lds(
      (const __attribute__((address_space(1))) void*)g,
      (__attribute__((address_space(3))) void*)l, 16, 0, 0);
}

__device__ __forceinline__ bool find_expert(const int* cnt, int p0, int& eSel,
                                            int& realEnd) {
  int base = 0;
  for (int i = 0; i < NE; i++) {
    int c = cnt[i];
    int pad = (c + 127) & ~127;
    if (p0 < base + pad) { eSel = i; realEnd = base + c; return p0 < base + c; }
    base += pad;
  }
  return false;
}

// ---------- init ----------
__global__ void init_kernel(int* __restrict__ cnt, int* __restrict__ fill) {
  int i = threadIdx.x;
  if (i < NE) { cnt[i] = 0; fill[i] = 0; }
}

// ---------- fp32 -> bf16 ----------
__global__ __launch_bounds__(256) void cvt_kernel(const float* __restrict__ s,
                                                  unsigned short* __restrict__ d,
                                                  int n) {
  int i = (blockIdx.x * 256 + threadIdx.x) * 8;
  if (i >= n) return;
  float4 a = *(const float4*)(s + i);
  float4 b = *(const float4*)(s + i + 4);
  *(u16x8*)(d + i) = cvt8(a, b);
}

// ---------- gate ----------
__global__ __launch_bounds__(256) void gate_kernel(
    const float* __restrict__ x, const float* __restrict__ gw,
    const float* __restrict__ gb, int* __restrict__ cnt,
    int* __restrict__ topk_idx, float* __restrict__ topk_w) {
  const int wave = threadIdx.x >> 6;
  const int lane = threadIdx.x & 63;
  const int t = blockIdx.x * 4 + wave;
  if (t >= T_TOKENS) return;
  const float* xt = x + (size_t)t * DIMK;

  float p[NE];
#pragma unroll
  for (int e = 0; e < NE; e++) p[e] = 0.0f;
  for (int d = lane; d < DIMK; d += 64) {
    float xv = xt[d];
#pragma unroll
    for (int e = 0; e < NE; e++) p[e] += xv * gw[e * DIMK + d];
  }
#pragma unroll
  for (int e = 0; e < NE; e++) {
#pragma unroll
    for (int off = 32; off > 0; off >>= 1) p[e] += __shfl_xor(p[e], off, 64);
  }
  if (lane == 0) {
    float m = p[0];
#pragma unroll
    for (int e = 1; e < NE; e++) m = fmaxf(m, p[e]);
    float s[NE]; float den = 0.0f;
#pragma unroll
    for (int e = 0; e < NE; e++) { s[e] = expf(p[e] - m); den += s[e]; }
    float inv = 1.0f / den;
    float sc[NE], bi[NE];
#pragma unroll
    for (int e = 0; e < NE; e++) { sc[e] = s[e] * inv; bi[e] = sc[e] + gb[e]; }
    int i0 = 0; float b0 = bi[0];
#pragma unroll
    for (int e = 1; e < NE; e++) if (bi[e] > b0) { b0 = bi[e]; i0 = e; }
    int i1 = -1; float b1 = -1e30f;
#pragma unroll
    for (int e = 0; e < NE; e++) if (e != i0 && bi[e] > b1) { b1 = bi[e]; i1 = e; }
    topk_idx[t * 2 + 0] = i0;
    topk_idx[t * 2 + 1] = i1;
    topk_w[t * 2 + 0] = sc[i0];
    topk_w[t * 2 + 1] = sc[i1];
    atomicAdd(&cnt[i0], 1);
    atomicAdd(&cnt[i1], 1);
  }
}

// ---------- scatter ----------
__global__ __launch_bounds__(256) void scatter_kernel(
    const int* __restrict__ cnt, int* __restrict__ fill,
    const int* __restrict__ topk_idx, const float* __restrict__ topk_w,
    int* __restrict__ pair_tok, float* __restrict__ pair_w) {
  int t = blockIdx.x * blockDim.x + threadIdx.x;
  if (t >= T_TOKENS) return;
  int offp[NE];
  int o = 0;
#pragma unroll
  for (int e = 0; e < NE; e++) { offp[e] = o; o += (cnt[e] + 127) & ~127; }
#pragma unroll
  for (int k = 0; k < 2; k++) {
    int e = topk_idx[t * 2 + k];
    int pos = atomicAdd(&fill[e], 1);
    int p = offp[e] + pos;
    pair_tok[p] = t;
    pair_w[p] = topk_w[t * 2 + k];
  }
}

// ---------- GEMM 1: H = silu(A@W1^T)*(A@W3^T) ----------
// block tile: 128M x 64N; 4 waves, each 64M x 32N per matrix
template <bool ROUTED, bool BBF16>
__global__ __launch_bounds__(256) void h_mfma(
    const unsigned short* __restrict__ xb, const void* __restrict__ w1p,
    const void* __restrict__ w3p, const int* __restrict__ cnt,
    const int* __restrict__ pair_tok, unsigned short* __restrict__ H) {
  const int p0 = blockIdx.y * 128;
  int realEnd = T_TOKENS, eSel = 0;
  if (ROUTED) {
    if (!find_expert(cnt, p0, eSel, realEnd)) return;
  }
  const size_t wOff = (size_t)eSel * INTER * DIMK;

  const int tid = threadIdx.x;
  const int lane = tid & 63;
  const int wv = tid >> 6;
  const int wm = (wv & 1) * 64, wn = (wv >> 1) * 32;
  const int lm = lane & 15, quad = lane >> 4;
  const int n0 = blockIdx.x * 64;

  const int srow = tid >> 2;
  const int skg = (tid & 3) * 8;

  int pa0 = p0 + srow, pa1 = p0 + srow + 64;
  int tok0, tok1;
  if (ROUTED) {
    tok0 = pair_tok[pa0 < realEnd ? pa0 : realEnd - 1];
    tok1 = pair_tok[pa1 < realEnd ? pa1 : realEnd - 1];
  } else { tok0 = pa0; tok1 = pa1; }
  const unsigned short* aSrc0 = xb + (size_t)tok0 * DIMK + skg;
  const unsigned short* aSrc1 = xb + (size_t)tok1 * DIMK + skg;

  const unsigned short* b1Src = nullptr; const unsigned short* b3Src = nullptr;
  const float* b1f32 = nullptr; const float* b3f32 = nullptr;
  if constexpr (BBF16) {
    b1Src = (const unsigned short*)w1p + wOff + (size_t)(n0 + srow) * DIMK + skg;
    b3Src = (const unsigned short*)w3p + wOff + (size_t)(n0 + srow) * DIMK + skg;
  } else {
    b1f32 = (const float*)w1p + wOff + (size_t)(n0 + srow) * DIMK + skg;
    b3f32 = (const float*)w3p + wOff + (size_t)(n0 + srow) * DIMK + skg;
  }

  __shared__ unsigned short As[128 * 32];
  __shared__ unsigned short B1s[64 * 32];
  __shared__ unsigned short B3s[64 * 32];

  f32x4 acc1[4][2] = {};
  f32x4 acc3[4][2] = {};

  for (int k0 = 0; k0 < DIMK; k0 += 32) {
    u16x8 b1v, b3v;
    if constexpr (!BBF16) {
      const float4* p1 = (const float4*)(b1f32 + k0);
      const float4* p3 = (const float4*)(b3f32 + k0);
      float4 a1 = p1[0], b1 = p1[1], a3 = p3[0], b3 = p3[1];
      b1v = cvt8(a1, b1);
      b3v = cvt8(a3, b3);
    }
    __syncthreads();
    gl_lds16(aSrc0 + k0, As + tid * 8);
    gl_lds16(aSrc1 + k0, As + 2048 + tid * 8);
    if constexpr (BBF16) {
      gl_lds16(b1Src + k0, B1s + tid * 8);
      gl_lds16(b3Src + k0, B3s + tid * 8);
    } else {
      *(u16x8*)(B1s + tid * 8) = b1v;
      *(u16x8*)(B3s + tid * 8) = b3v;
    }
    __syncthreads();

    bf16x8 af[4], b1r[2], b3r[2];
#pragma unroll
    for (int mi = 0; mi < 4; mi++)
      af[mi] = *(const bf16x8*)&As[(wm + mi * 16 + lm) * 32 + quad * 8];
#pragma unroll
    for (int ni = 0; ni < 2; ni++) {
      b1r[ni] = *(const bf16x8*)&B1s[(wn + ni * 16 + lm) * 32 + quad * 8];
      b3r[ni] = *(const bf16x8*)&B3s[(wn + ni * 16 + lm) * 32 + quad * 8];
    }
#pragma unroll
    for (int mi = 0; mi < 4; mi++) {
#pragma unroll
      for (int ni = 0; ni < 2; ni++) {
        acc1[mi][ni] = __builtin_amdgcn_mfma_f32_16x16x32_bf16(
            af[mi], b1r[ni], acc1[mi][ni], 0, 0, 0);
        acc3[mi][ni] = __builtin_amdgcn_mfma_f32_16x16x32_bf16(
            af[mi], b3r[ni], acc3[mi][ni], 0, 0, 0);
      }
    }
  }

#pragma unroll
  for (int mi = 0; mi < 4; mi++) {
#pragma unroll
    for (int r = 0; r < 4; r++) {
      int row = p0 + wm + mi * 16 + quad * 4 + r;
      if (!ROUTED || row < realEnd) {
        unsigned short* hrow = H + (size_t)row * INTER + n0 + wn + lm;
#pragma unroll
        for (int ni = 0; ni < 2; ni++) {
          float v = silu_f(acc1[mi][ni][r]) * acc3[mi][ni][r];
          hrow[ni * 16] = f2bf(v);
        }
      }
    }
  }
}

// ---------- GEMM 2: out = H @ W2^T (128x128 block, 64x64/wave) ----------
template <bool ROUTED, bool BBF16>
__global__ __launch_bounds__(256) void out_mfma(
    const unsigned short* __restrict__ H, const void* __restrict__ w2p,
    const int* __restrict__ cnt, const int* __restrict__ pair_tok,
    const float* __restrict__ pair_w, float* __restrict__ out) {
  const int p0 = blockIdx.y * 128;
  int realEnd = T_TOKENS, eSel = 0;
  if (ROUTED) {
    if (!find_expert(cnt, p0, eSel, realEnd)) return;
  }
  const size_t wOff = (size_t)eSel * DIMK * INTER;

  const int tid = threadIdx.x;
  const int lane = tid & 63;
  const int wv = tid >> 6;
  const int wm = (wv & 1) * 64, wn = (wv >> 1) * 64;
  const int lm = lane & 15, quad = lane >> 4;
  const int n0 = blockIdx.x * 128;

  const int srow = tid >> 2;
  const int skg = (tid & 3) * 8;

  const unsigned short* aSrc0 = H + (size_t)(p0 + srow) * INTER + skg;
  const unsigned short* aSrc1 = H + (size_t)(p0 + srow + 64) * INTER + skg;

  const unsigned short* bSrc0 = nullptr; const unsigned short* bSrc1 = nullptr;
  const float* bF0 = nullptr; const float* bF1 = nullptr;
  if constexpr (BBF16) {
    bSrc0 = (const unsigned short*)w2p + wOff + (size_t)(n0 + srow) * INTER + skg;
    bSrc1 = (const unsigned short*)w2p + wOff + (size_t)(n0 + srow + 64) * INTER + skg;
  } else {
    bF0 = (const float*)w2p + wOff + (size_t)(n0 + srow) * INTER + skg;
    bF1 = (const float*)w2p + wOff + (size_t)(n0 + srow + 64) * INTER + skg;
  }

  __shared__ unsigned short As[128 * 32];
  __shared__ unsigned short Bs[128 * 32];

  f32x4 acc[4][4] = {};

  for (int k0 = 0; k0 < INTER; k0 += 32) {
    u16x8 bv0, bv1;
    if constexpr (!BBF16) {
      const float4* q0 = (const float4*)(bF0 + k0);
      const float4* q1 = (const float4*)(bF1 + k0);
      float4 a0 = q0[0], c0 = q0[1], a1 = q1[0], c1 = q1[1];
      bv0 = cvt8(a0, c0);
      bv1 = cvt8(a1, c1);
    }
    __syncthreads();
    gl_lds16(aSrc0 + k0, As + tid * 8);
    gl_lds16(aSrc1 + k0, As + 2048 + tid * 8);
    if constexpr (BBF16) {
      gl_lds16(bSrc0 + k0, Bs + tid * 8);
      gl_lds16(bSrc1 + k0, Bs + 2048 + tid * 8);
    } else {
      *(u16x8*)(Bs + tid * 8) = bv0;
      *(u16x8*)(Bs + 2048 + tid * 8) = bv1;
    }
    __syncthreads();

    bf16x8 af[4], bf[4];
#pragma unroll
    for (int mi = 0; mi < 4; mi++)
      af[mi] = *(const bf16x8*)&As[(wm + mi * 16 + lm) * 32 + quad * 8];
#pragma unroll
    for (int ni = 0; ni < 4; ni++)
      bf[ni] = *(const bf16x8*)&Bs[(wn + ni * 16 + lm) * 32 + quad * 8];
#pragma unroll
    for (int mi = 0; mi < 4; mi++) {
#pragma unroll
      for (int ni = 0; ni < 4; ni++) {
        acc[mi][ni] = __builtin_amdgcn_mfma_f32_16x16x32_bf16(
            af[mi], bf[ni], acc[mi][ni], 0, 0, 0);
      }
    }
  }

#pragma unroll
  for (int mi = 0; mi < 4; mi++) {
#pragma unroll
    for (int r = 0; r < 4; r++) {
      int row = p0 + wm + mi * 16 + quad * 4 + r;
      if (ROUTED) {
        if (row < realEnd) {
          int tok = pair_tok[row];
          float wgt = pair_w[row];
          float* orow = out + (size_t)tok * DIMK + n0 + wn + lm;
#pragma unroll
          for (int ni = 0; ni < 4; ni++)
            atomicAdd(&orow[ni * 16], acc[mi][ni][r] * wgt);
        }
      } else {
        float* orow = out + (size_t)row * DIMK + n0 + wn + lm;
#pragma unroll
        for (int ni = 0; ni < 4; ni++)
          orow[ni * 16] = acc[mi][ni][r];
      }
    }
  }
}

// ---------- launch ----------
extern "C" void kernel_launch(void* const* d_in, const int* in_sizes, int n_in,
                              void* d_out, int out_size, void* d_ws, size_t ws_size,
                              hipStream_t stream) {
  const float* x   = (const float*)d_in[0];
  const float* gw  = (const float*)d_in[1];
  const float* gb  = (const float*)d_in[2];
  const float* w1  = (const float*)d_in[3];
  const float* w2  = (const float*)d_in[4];
  const float* w3  = (const float*)d_in[5];
  const float* sw1 = (const float*)d_in[6];
  const float* sw2 = (const float*)d_in[7];
  const float* sw3 = (const float*)d_in[8];
  float* out = (float*)d_out;
  (void)in_sizes; (void)n_in; (void)out_size;

  char* ws = (char*)d_ws;
  int* cnt = (int*)ws;
  int* fill = cnt + 8;
  int* topk_idx = fill + 8;
  float* topk_w = (float*)(topk_idx + 2 * T_TOKENS);
  int* pair_tok = (int*)(topk_w + 2 * T_TOKENS);
  float* pair_w = (float*)(pair_tok + CAP);
  size_t off = (size_t)((char*)(pair_w + CAP) - ws);
  off = (off + 255) & ~(size_t)255;
  unsigned short* H = (unsigned short*)(ws + off);
  off += (size_t)CAP * INTER * 2;
  unsigned short* xb = (unsigned short*)(ws + off);
  off += (size_t)T_TOKENS * DIMK * 2;

  const size_t nRW = (size_t)NE * INTER * DIMK;   // 16.8M elems per routed matrix
  const size_t nSW = (size_t)INTER * DIMK;        // 2.1M elems per shared matrix
  const size_t avail = (ws_size > off) ? ws_size - off : 0;

  // Tier A: all six bf16 buffers distinct (needs 113.2 MB free)
  // Tier B: one region, time-multiplexed (needs 67.2 MB free)
  // Tier C: fallback, in-GEMM fp32->bf16 conversion
  const bool TIER_A = avail >= (3 * nRW + 3 * nSW) * 2;
  const bool TIER_B = !TIER_A && avail >= 2 * nRW * 2;

  unsigned short *w1b, *w3b, *w2b, *sw1b, *sw3b, *sw2b;
  if (TIER_A) {
    unsigned short* R = (unsigned short*)(ws + off);
    w1b = R;            w3b = R + nRW;      w2b = R + 2 * nRW;
    sw1b = R + 3 * nRW; sw3b = sw1b + nSW;  sw2b = sw1b + 2 * nSW;
  } else if (TIER_B) {
    unsigned short* R = (unsigned short*)(ws + off);
    w1b = R; w3b = R + nRW;   // w1+w3 phase
    w2b = R;                  // reuses after routed h
    sw1b = R; sw3b = R + nSW; // shared phase
    sw2b = R;                 // reuses after shared h
  } else {
    w1b = w3b = w2b = sw1b = sw3b = sw2b = nullptr;
  }

  init_kernel<<<1, 64, 0, stream>>>(cnt, fill);
  cvt_kernel<<<(T_TOKENS * DIMK) / 2048, 256, 0, stream>>>(x, xb, T_TOKENS * DIMK);
  gate_kernel<<<T_TOKENS / 4, 256, 0, stream>>>(x, gw, gb, cnt, topk_idx, topk_w);
  scatter_kernel<<<T_TOKENS / 256, 256, 0, stream>>>(cnt, fill, topk_idx, topk_w,
                                                     pair_tok, pair_w);

  if (TIER_A || TIER_B) {
    // shared expert
    cvt_kernel<<<(int)(nSW / 2048), 256, 0, stream>>>(sw1, sw1b, (int)nSW);
    cvt_kernel<<<(int)(nSW / 2048), 256, 0, stream>>>(sw3, sw3b, (int)nSW);
    h_mfma<false, true><<<dim3(INTER / 64, T_TOKENS / 128), 256, 0, stream>>>(
        xb, sw1b, sw3b, nullptr, nullptr, H);
    cvt_kernel<<<(int)(nSW / 2048), 256, 0, stream>>>(sw2, sw2b, (int)nSW);
    out_mfma<false, true><<<dim3(DIMK / 128, T_TOKENS / 128), 256, 0, stream>>>(
        H, sw2b, nullptr, nullptr, nullptr, out);
    // routed experts
    cvt_kernel<<<(int)(nRW / 2048), 256, 0, stream>>>(w1, w1b, (int)nRW);
    cvt_kernel<<<(int)(nRW / 2048), 256, 0, stream>>>(w3, w3b, (int)nRW);
    h_mfma<true, true><<<dim3(INTER / 64, CAP / 128), 256, 0, stream>>>(
        xb, w1b, w3b, cnt, pair_tok, H);
    cvt_kernel<<<(int)(nRW / 2048), 256, 0, stream>>>(w2, w2b, (int)nRW);
    out_mfma<true, true><<<dim3(DIMK / 128, CAP / 128), 256, 0, stream>>>(
        H, w2b, cnt, pair_tok, pair_w, out);
  } else {
    h_mfma<false, false><<<dim3(INTER / 64, T_TOKENS / 128), 256, 0, stream>>>(
        xb, sw1, sw3, nullptr, nullptr, H);
    out_mfma<false, false><<<dim3(DIMK / 128, T_TOKENS / 128), 256, 0, stream>>>(
        H, sw2, nullptr, nullptr, nullptr, out);
    h_mfma<true, false><<<dim3(INTER / 64, CAP / 128), 256, 0, stream>>>(
        xb, w1, w3, cnt, pair_tok, H);
    out_mfma<true, false><<<dim3(DIMK / 128, CAP / 128), 256, 0, stream>>>(
        H, w2, cnt, pair_tok, pair_w, out);
  }
}